// Round 8
// baseline (417.776 us; speedup 1.0000x reference)
//
#include <hip/hip_runtime.h>
#include <math.h>

#define L_DIM 8
#define B_DIM 8
#define C_DIM 512
#define D_DIM 4096
#define NPAIR 64          // L*B
#define KSEL_CNT 52       // 52nd smallest = 0-based sorted index 51 (k = C/10)
#define NSLAB 128         // D_DIM / 32

typedef __attribute__((ext_vector_type(8))) _Float16 half8;  // MFMA f16 operand
typedef __attribute__((ext_vector_type(4))) float f32x4;     // MFMA acc

// chunk-index bank swizzle (0 conflicts measured R5-R7)
__device__ __forceinline__ int swz(int c) { return c ^ (((c >> 4) & 3) << 1); }

__device__ __forceinline__ uint4 cvth8(float4 f0, float4 f1) {
    half8 h;
    h[0] = (_Float16)f0.x; h[1] = (_Float16)f0.y;
    h[2] = (_Float16)f0.z; h[3] = (_Float16)f0.w;
    h[4] = (_Float16)f1.x; h[5] = (_Float16)f1.y;
    h[6] = (_Float16)f1.z; h[7] = (_Float16)f1.w;
    return __builtin_bit_cast(uint4, h);
}

// raw barrier WITHOUT vmcnt drain: LDS ops must be complete (cross-wave
// visibility), but global loads stay in flight across the barrier. This is
// the one thing __syncthreads cannot express (it drains vmcnt(0)).
#define BARRIER_KEEP_LOADS() \
    asm volatile("s_waitcnt lgkmcnt(0)\n\ts_barrier" ::: "memory")

// ---------------------------------------------------------------------------
// Kernel 1: G = F*F^T per (l,b) pair, fp16 MFMA. Tile 256(M)x128(N), 8 blocks
// per pair (2x4), 512 threads = 8 waves (4x2), wave tile 64x64, acc[4][4]
// (no-spill shape per R3/R5/R7). K-loop: LDS double-buffer, ONE raw barrier
// per slab, and 2-slab-deep register prefetch (two named sets, unroll x2,
// static indexing) -- loads issued at slab s are first waited at slab s+2's
// cvt via compiler-counted vmcnt, ~2 slab bodies (>600 cyc) later.
// bid = tile*np + pl -> pair's 8 blocks share an XCD when np%8==0.
// ---------------------------------------------------------------------------
__global__ __launch_bounds__(512)
void gram_mfma(const float* __restrict__ F, float* __restrict__ G,
               float* __restrict__ diag, int pair0, int np) {
    __shared__ uint4 sA[2][1024], sB[2][512];    // 48 KB

    const int bid = blockIdx.x;
    const int pl  = bid % np;       // chunk-local pair
    const int tid = bid / np;       // 0..7
    const int ti = tid >> 2, tj = tid & 3;   // 2 row-tiles x 4 col-tiles
    const int p = pair0 + pl;

    const float* Fp = F + (size_t)p * C_DIM * D_DIM;
    float* Gp = G + (size_t)pl * C_DIM * C_DIM;

    const int t = threadIdx.x, lane = t & 63, w = t >> 6;   // 8 waves
    const int wr = w >> 1, wc = w & 1;                       // 4x2 wave grid

    // staging: thread t covers A rows r0, r0+128 and B row r0; k-chunk kc*8..+8
    const int r0 = t >> 2, kc = t & 3;
    const int cA  = (r0 >> 4) * 64 + (r0 & 15) + kc * 16;   // frag-linear chunk
    const int st0 = swz(cA), st1 = swz(cA + 512);

    const float* aP = Fp + (size_t)(ti * 256 + r0) * D_DIM + kc * 8;
    const float* bP = Fp + (size_t)(tj * 128 + r0) * D_DIM + kc * 8;
    const size_t rowHop = (size_t)128 * D_DIM;

    f32x4 acc[4][4];
#pragma unroll
    for (int m = 0; m < 4; ++m)
#pragma unroll
        for (int n = 0; n < 4; ++n) acc[m][n] = (f32x4){0.f, 0.f, 0.f, 0.f};

    // frag read addresses (loop-invariant)
    int rdA[4], rdB[4];
#pragma unroll
    for (int m = 0; m < 4; ++m) rdA[m] = swz((wr * 4 + m) * 64 + lane);
#pragma unroll
    for (int n = 0; n < 4; ++n) rdB[n] = swz((wc * 4 + n) * 64 + lane);

    // prologue: issue slab 0 into set E, slab 1 into set O (both in flight)
    float4 eA0 = *(const float4*)(aP),          eA1 = *(const float4*)(aP + 4);
    float4 eA2 = *(const float4*)(aP + rowHop), eA3 = *(const float4*)(aP + rowHop + 4);
    float4 eB0 = *(const float4*)(bP),          eB1 = *(const float4*)(bP + 4);
    float4 oA0 = *(const float4*)(aP + 32),          oA1 = *(const float4*)(aP + 36);
    float4 oA2 = *(const float4*)(aP + rowHop + 32), oA3 = *(const float4*)(aP + rowHop + 36);
    float4 oB0 = *(const float4*)(bP + 32),          oB1 = *(const float4*)(bP + 36);

    for (int s = 0; s < NSLAB; s += 2) {
        // ---------------- even slab s: set E -> buf 0 ----------------
        // cvt waits (counted vmcnt) only on set E; set O stays in flight
        sA[0][st0] = cvth8(eA0, eA1);
        sA[0][st1] = cvth8(eA2, eA3);
        sB[0][st0] = cvth8(eB0, eB1);
        BARRIER_KEEP_LOADS();
        if (s + 2 < NSLAB) {   // issue slab s+2 into E; waited at next even cvt
            const float* ap = aP + (s + 2) * 32;
            const float* bp = bP + (s + 2) * 32;
            eA0 = *(const float4*)(ap);          eA1 = *(const float4*)(ap + 4);
            eA2 = *(const float4*)(ap + rowHop); eA3 = *(const float4*)(ap + rowHop + 4);
            eB0 = *(const float4*)(bp);          eB1 = *(const float4*)(bp + 4);
        }
        {
            half8 ah[4], bh[4];
#pragma unroll
            for (int m = 0; m < 4; ++m) ah[m] = __builtin_bit_cast(half8, sA[0][rdA[m]]);
#pragma unroll
            for (int n = 0; n < 4; ++n) bh[n] = __builtin_bit_cast(half8, sB[0][rdB[n]]);
#pragma unroll
            for (int m = 0; m < 4; ++m)
#pragma unroll
                for (int n = 0; n < 4; ++n)
                    acc[m][n] = __builtin_amdgcn_mfma_f32_16x16x32_f16(ah[m], bh[n], acc[m][n], 0, 0, 0);
        }
        // ---------------- odd slab s+1: set O -> buf 1 ----------------
        // buf1's previous readers (slab s-1) finished before slab s's barrier
        sA[1][st0] = cvth8(oA0, oA1);
        sA[1][st1] = cvth8(oA2, oA3);
        sB[1][st0] = cvth8(oB0, oB1);
        BARRIER_KEEP_LOADS();
        if (s + 3 < NSLAB) {   // issue slab s+3 into O
            const float* ap = aP + (s + 3) * 32;
            const float* bp = bP + (s + 3) * 32;
            oA0 = *(const float4*)(ap);          oA1 = *(const float4*)(ap + 4);
            oA2 = *(const float4*)(ap + rowHop); oA3 = *(const float4*)(ap + rowHop + 4);
            oB0 = *(const float4*)(bp);          oB1 = *(const float4*)(bp + 4);
        }
        {
            half8 ah[4], bh[4];
#pragma unroll
            for (int m = 0; m < 4; ++m) ah[m] = __builtin_bit_cast(half8, sA[1][rdA[m]]);
#pragma unroll
            for (int n = 0; n < 4; ++n) bh[n] = __builtin_bit_cast(half8, sB[1][rdB[n]]);
#pragma unroll
            for (int m = 0; m < 4; ++m)
#pragma unroll
                for (int n = 0; n < 4; ++n)
                    acc[m][n] = __builtin_amdgcn_mfma_f32_16x16x32_f16(ah[m], bh[n], acc[m][n], 0, 0, 0);
        }
    }

    // epilogue: C/D map col=lane&15, row=(lane>>4)*4+reg (verified R5-R7)
    const int fr = (lane >> 4) * 4, fc = lane & 15;
#pragma unroll
    for (int m = 0; m < 4; ++m) {
        const int row = ti * 256 + wr * 64 + m * 16 + fr;
#pragma unroll
        for (int n = 0; n < 4; ++n) {
            const int col = tj * 128 + wc * 64 + n * 16 + fc;
#pragma unroll
            for (int j = 0; j < 4; ++j)
                Gp[(size_t)(row + j) * C_DIM + col] = acc[m][n][j];
        }
    }
    // diag: tile overlaps diagonal iff tj>>1 == ti; local row==col needs
    // wr == wc + 2*(tj&1), m==n, fr+j==fc.
    if ((tj >> 1) == ti && wr == wc + 2 * (tj & 1) && ((fc >> 2) == (lane >> 4))) {
        const int j = lane & 3;
#pragma unroll
        for (int m = 0; m < 4; ++m)
            diag[(size_t)p * C_DIM + ti * 256 + wr * 64 + m * 16 + fc] = acc[m][m][j];
    }
}

// ---------------------------------------------------------------------------
// Kernel 2: one wave per row. d2[m] = sq[n]+sq[m]-2G[n,m] in 8 regs/lane;
// bit-pattern bisection -> exact 52nd smallest (attained value).
// ---------------------------------------------------------------------------
__global__ __launch_bounds__(256)
void select_kernel(const float* __restrict__ G, const float* __restrict__ diag,
                   float* __restrict__ kth, int pair0) {
    const int w = threadIdx.x >> 6, lane = threadIdx.x & 63;
    const int row = blockIdx.x * 4 + w;
    const int pl  = blockIdx.y;
    const int p   = pair0 + pl;

    const float* Grow = G + ((size_t)pl * C_DIM + row) * C_DIM;
    const float* dg   = diag + (size_t)p * C_DIM;
    const float  sqn  = dg[row];

    const float4 g0 = *(const float4*)(Grow + lane * 8);
    const float4 g1 = *(const float4*)(Grow + lane * 8 + 4);
    const float4 d0 = *(const float4*)(dg + lane * 8);
    const float4 d1 = *(const float4*)(dg + lane * 8 + 4);

    float v[8];
    v[0] = fmaxf(sqn + d0.x - 2.f * g0.x, 0.f);
    v[1] = fmaxf(sqn + d0.y - 2.f * g0.y, 0.f);
    v[2] = fmaxf(sqn + d0.z - 2.f * g0.z, 0.f);
    v[3] = fmaxf(sqn + d0.w - 2.f * g0.w, 0.f);
    v[4] = fmaxf(sqn + d1.x - 2.f * g1.x, 0.f);
    v[5] = fmaxf(sqn + d1.y - 2.f * g1.y, 0.f);
    v[6] = fmaxf(sqn + d1.z - 2.f * g1.z, 0.f);
    v[7] = fmaxf(sqn + d1.w - 2.f * g1.w, 0.f);

    unsigned lo = 0u, hi = 0x47800000u;   // 65536.0f >> max d2 (~9e3)
    while (lo < hi) {
        const unsigned mid = (lo + hi) >> 1;
        const float piv = __uint_as_float(mid);
        int c = 0;
#pragma unroll
        for (int i = 0; i < 8; ++i) c += (v[i] <= piv) ? 1 : 0;
#pragma unroll
        for (int off = 32; off > 0; off >>= 1) c += __shfl_xor(c, off);
        if (c >= KSEL_CNT) hi = mid; else lo = mid + 1;
    }
    if (lane == 0)
        kth[(size_t)p * C_DIM + row] = sqrtf(fmaxf(__uint_as_float(lo), 1e-12f));
}

// ---------------------------------------------------------------------------
// Kernel 3: per-layer fp64 fixed-order sum of 4096 kth-distances.
// ---------------------------------------------------------------------------
__global__ __launch_bounds__(256)
void reduce_kernel(const float* __restrict__ kth, double* __restrict__ hsum) {
    __shared__ double sd[256];
    const int l = blockIdx.x;
    const float* base = kth + (size_t)l * B_DIM * C_DIM;
    double acc = 0.0;
    for (int i = threadIdx.x; i < B_DIM * C_DIM; i += 256)
        acc += (double)base[i];
    sd[threadIdx.x] = acc;
    __syncthreads();
    for (int sstep = 128; sstep > 0; sstep >>= 1) {
        if (threadIdx.x < sstep) sd[threadIdx.x] += sd[threadIdx.x + sstep];
        __syncthreads();
    }
    if (threadIdx.x == 0) hsum[l] = sd[0];
}

// ---------------------------------------------------------------------------
// Kernel 4: ents = log(S+1); var(d1,ddof=1)+var(d2,ddof=1).
// ---------------------------------------------------------------------------
__global__ void final_kernel(const double* __restrict__ hsum, float* __restrict__ out) {
    double ents[L_DIM];
    for (int l = 0; l < L_DIM; ++l) ents[l] = log(hsum[l] + 1.0);
    const double d1[2] = { ents[2] - ents[1], ents[3] - ents[2] };
    const double d2[4] = { ents[4] - ents[3], ents[5] - ents[4],
                           ents[6] - ents[5], ents[7] - ents[6] };
    const double m1 = (d1[0] + d1[1]) * 0.5;
    const double v1 = (d1[0] - m1) * (d1[0] - m1) + (d1[1] - m1) * (d1[1] - m1);
    double m2 = 0.0;
    for (int i = 0; i < 4; ++i) m2 += d2[i];
    m2 *= 0.25;
    double v2 = 0.0;
    for (int i = 0; i < 4; ++i) v2 += (d2[i] - m2) * (d2[i] - m2);
    v2 /= 3.0;
    out[0] = (float)(v1 + v2);
}

// ---------------------------------------------------------------------------
extern "C" void kernel_launch(void* const* d_in, const int* in_sizes, int n_in,
                              void* d_out, int out_size, void* d_ws, size_t ws_size,
                              hipStream_t stream) {
    const float* net = (const float*)d_in[0];
    float* out = (float*)d_out;
    char* ws = (char*)d_ws;

    double* hsum = (double*)ws;
    float*  diag = (float*)(ws + 4096);
    float*  kth  = (float*)(ws + 4096 + 131072);
    const size_t gOff = 4096 + 2 * 131072;
    float*  G    = (float*)(ws + gOff);

    const size_t perPair = (size_t)C_DIM * C_DIM * sizeof(float);
    const size_t avail = ws_size > gOff ? ws_size - gOff : 0;
    int chunk = (int)(avail / perPair);
    if (chunk > NPAIR) chunk = NPAIR;
    if (chunk < 1) chunk = 1;

    for (int p0 = 0; p0 < NPAIR; p0 += chunk) {
        const int np = (NPAIR - p0) < chunk ? (NPAIR - p0) : chunk;
        gram_mfma<<<dim3(8 * np), dim3(512), 0, stream>>>(net, G, diag, p0, np);
        select_kernel<<<dim3(C_DIM / 4, np), dim3(256), 0, stream>>>(G, diag, kth, p0);
    }
    reduce_kernel<<<dim3(L_DIM), dim3(256), 0, stream>>>(kth, hsum);
    final_kernel<<<dim3(1), dim3(1), 0, stream>>>(hsum, out);
}

// Round 10
// 352.322 us; speedup vs baseline: 1.1858x; 1.1858x over previous
//
#include <hip/hip_runtime.h>
#include <math.h>

#define L_DIM 8
#define B_DIM 8
#define C_DIM 512
#define D_DIM 4096
#define NPAIR 64          // L*B
#define KSEL_CNT 52       // 52nd smallest = 0-based sorted index 51 (k = C/10)
#define NSLAB 128         // D_DIM / 32

typedef __attribute__((ext_vector_type(8))) _Float16 half8;   // MFMA f16 operand
typedef __attribute__((ext_vector_type(2))) __fp16 fp16x2;    // cvt_pkrtz result type
typedef __attribute__((ext_vector_type(4))) float f32x4;      // MFMA acc

// chunk-index bank swizzle (0 conflicts measured R5-R8)
__device__ __forceinline__ int swz(int c) { return c ^ (((c >> 4) & 3) << 1); }

// 8x f32 -> 8x f16 via v_cvt_pkrtz_f16_f32: 4 VALU ops (vs ~12 for cast+pack).
// RTZ bias is layer-uniform in S and cancels in ents differences.
__device__ __forceinline__ uint4 pk8(float4 f0, float4 f1) {
    fp16x2 a = __builtin_amdgcn_cvt_pkrtz(f0.x, f0.y);
    fp16x2 b = __builtin_amdgcn_cvt_pkrtz(f0.z, f0.w);
    fp16x2 c = __builtin_amdgcn_cvt_pkrtz(f1.x, f1.y);
    fp16x2 d = __builtin_amdgcn_cvt_pkrtz(f1.z, f1.w);
    return make_uint4(__builtin_bit_cast(unsigned, a), __builtin_bit_cast(unsigned, b),
                      __builtin_bit_cast(unsigned, c), __builtin_bit_cast(unsigned, d));
}

// raw barrier WITHOUT vmcnt drain: LDS ops complete (cross-wave visibility),
// global loads stay in flight (what __syncthreads cannot express).
#define BARRIER_KEEP_LOADS() \
    asm volatile("s_waitcnt lgkmcnt(0)\n\ts_barrier" ::: "memory")

// ---------------------------------------------------------------------------
// Kernel 1: G = F*F^T per (l,b) pair, fp16 MFMA. R3's proven geometry:
// 128x128 upper-triangle tiles (+mirror), 10 tiles/pair, 256 threads
// (4 waves, 2x2, 64x64/wave, acc[4][4]), 16 KB LDS single-buffer, XCD-
// clustered bid mapping (pair's 10 blocks share an XCD). Per-slab order:
//   barrier1(lgkm) -> cvt(vmcnt wait) -> ds_write -> ISSUE next loads
//   -> barrier2(lgkm) -> frag reads -> MFMA
// so prefetch loads span barrier2+ds_reads+MFMA+barrier1 (~500 cyc).
// ---------------------------------------------------------------------------
__global__ __launch_bounds__(256)
void gram_mfma(const float* __restrict__ F, float* __restrict__ G,
               float* __restrict__ diag, int pair0, int np) {
    __shared__ uint4 sA[512], sB[512];    // 16 KB total

    int bidx = blockIdx.x;
    int pl, tileid;
    if ((np & 7) == 0) {          // XCD clustering: pair pl -> blocks == pl (mod 8)
        const int r = bidx & 7, q = bidx >> 3;
        pl = r + 8 * (q / 10);
        tileid = q % 10;
    } else {
        pl = bidx / 10;
        tileid = bidx % 10;
    }
    const int p = pair0 + pl;

    int ti = 0, rem = tileid;     // (ti,tj), ti<=tj over 4x4 tile grid
    while (rem >= (4 - ti)) { rem -= (4 - ti); ++ti; }
    const int tj = ti + rem;

    const float* Fp = F + (size_t)p * C_DIM * D_DIM;
    float* Gp = G + (size_t)pl * C_DIM * C_DIM;

    const int t = threadIdx.x, lane = t & 63, w = t >> 6;
    const int wr = w >> 1, wc = w & 1;

    // staging: thread t covers rows r0 and r0+64, k-chunk kc*8..+8
    const int r0 = t >> 2, kc = t & 3;
    const int cA = (r0 >> 4) * 64 + (r0 & 15) + kc * 16;   // frag-linear chunk
    const int st0 = swz(cA), st1 = swz(cA + 256);

    const float* aP = Fp + (size_t)(ti * 128 + r0) * D_DIM + kc * 8;
    const float* bP = Fp + (size_t)(tj * 128 + r0) * D_DIM + kc * 8;
    const size_t rowHop = (size_t)64 * D_DIM;

    f32x4 acc[4][4];
#pragma unroll
    for (int m = 0; m < 4; ++m)
#pragma unroll
        for (int n = 0; n < 4; ++n) acc[m][n] = (f32x4){0.f, 0.f, 0.f, 0.f};

    // frag read addresses (loop-invariant)
    int rdA[4], rdB[4];
#pragma unroll
    for (int m = 0; m < 4; ++m) rdA[m] = swz((wr * 4 + m) * 64 + lane);
#pragma unroll
    for (int n = 0; n < 4; ++n) rdB[n] = swz((wc * 4 + n) * 64 + lane);

    // prologue: issue slab-0 loads
    float4 fA0 = *(const float4*)(aP),          fA1 = *(const float4*)(aP + 4);
    float4 fA2 = *(const float4*)(aP + rowHop), fA3 = *(const float4*)(aP + rowHop + 4);
    float4 fB0 = *(const float4*)(bP),          fB1 = *(const float4*)(bP + 4);
    float4 fB2 = *(const float4*)(bP + rowHop), fB3 = *(const float4*)(bP + rowHop + 4);

    for (int s = 0; s < NSLAB; ++s) {
        BARRIER_KEEP_LOADS();   // barrier1: prior slab's frag reads consumed
        sA[st0] = pk8(fA0, fA1);   // vmcnt wait happens here (data dep)
        sA[st1] = pk8(fA2, fA3);
        sB[st0] = pk8(fB0, fB1);
        sB[st1] = pk8(fB2, fB3);
        if (s + 1 < NSLAB) {    // issue next-slab loads BEFORE barrier2:
            const float* ap = aP + (s + 1) * 32;   // they stay in flight across
            const float* bp = bP + (s + 1) * 32;   // barrier2+frags+MFMA+barrier1
            fA0 = *(const float4*)(ap);          fA1 = *(const float4*)(ap + 4);
            fA2 = *(const float4*)(ap + rowHop); fA3 = *(const float4*)(ap + rowHop + 4);
            fB0 = *(const float4*)(bp);          fB1 = *(const float4*)(bp + 4);
            fB2 = *(const float4*)(bp + rowHop); fB3 = *(const float4*)(bp + rowHop + 4);
        }
        BARRIER_KEEP_LOADS();   // barrier2: writes visible; loads NOT drained

        half8 ah[4], bh[4];
#pragma unroll
        for (int m = 0; m < 4; ++m) ah[m] = __builtin_bit_cast(half8, sA[rdA[m]]);
#pragma unroll
        for (int n = 0; n < 4; ++n) bh[n] = __builtin_bit_cast(half8, sB[rdB[n]]);
#pragma unroll
        for (int m = 0; m < 4; ++m)
#pragma unroll
            for (int n = 0; n < 4; ++n)
                acc[m][n] = __builtin_amdgcn_mfma_f32_16x16x32_f16(ah[m], bh[n], acc[m][n], 0, 0, 0);
    }

    // epilogue: C/D map col=lane&15, row=(lane>>4)*4+reg (verified R3-R8)
    const int gr0 = ti * 128 + wr * 64;
    const int gc0 = tj * 128 + wc * 64;
    const int fr = (lane >> 4) * 4;
    const int fc = lane & 15;
#pragma unroll
    for (int m = 0; m < 4; ++m)
#pragma unroll
        for (int n = 0; n < 4; ++n) {
            const int rr = gr0 + m * 16 + fr;
            const int cc = gc0 + n * 16 + fc;
#pragma unroll
            for (int j = 0; j < 4; ++j)
                Gp[(size_t)(rr + j) * C_DIM + cc] = acc[m][n][j];
        }
    if (ti != tj) {
        // mirror into the lower-triangle tile (G symmetric)
#pragma unroll
        for (int m = 0; m < 4; ++m)
#pragma unroll
            for (int n = 0; n < 4; ++n) {
                const int rr = gr0 + m * 16 + fr;
                const int cc = gc0 + n * 16 + fc;
#pragma unroll
                for (int j = 0; j < 4; ++j)
                    Gp[(size_t)cc * C_DIM + rr + j] = acc[m][n][j];
            }
    } else if (wr == wc && ((fc >> 2) == (lane >> 4))) {
        // diagonal extraction: row==col within frag m==n
        const int j = fc & 3;
#pragma unroll
        for (int m = 0; m < 4; ++m)
            diag[(size_t)p * C_DIM + gr0 + m * 16 + fc] = acc[m][m][j];
    }
}

// ---------------------------------------------------------------------------
// Kernel 2: one wave per row. d2[m] = sq[n]+sq[m]-2G[n,m] in 8 regs/lane;
// bit-pattern bisection -> exact 52nd smallest (attained value).
// ---------------------------------------------------------------------------
__global__ __launch_bounds__(256)
void select_kernel(const float* __restrict__ G, const float* __restrict__ diag,
                   float* __restrict__ kth, int pair0) {
    const int w = threadIdx.x >> 6, lane = threadIdx.x & 63;
    const int row = blockIdx.x * 4 + w;
    const int pl  = blockIdx.y;
    const int p   = pair0 + pl;

    const float* Grow = G + ((size_t)pl * C_DIM + row) * C_DIM;
    const float* dg   = diag + (size_t)p * C_DIM;
    const float  sqn  = dg[row];

    const float4 g0 = *(const float4*)(Grow + lane * 8);
    const float4 g1 = *(const float4*)(Grow + lane * 8 + 4);
    const float4 d0 = *(const float4*)(dg + lane * 8);
    const float4 d1 = *(const float4*)(dg + lane * 8 + 4);

    float v[8];
    v[0] = fmaxf(sqn + d0.x - 2.f * g0.x, 0.f);
    v[1] = fmaxf(sqn + d0.y - 2.f * g0.y, 0.f);
    v[2] = fmaxf(sqn + d0.z - 2.f * g0.z, 0.f);
    v[3] = fmaxf(sqn + d0.w - 2.f * g0.w, 0.f);
    v[4] = fmaxf(sqn + d1.x - 2.f * g1.x, 0.f);
    v[5] = fmaxf(sqn + d1.y - 2.f * g1.y, 0.f);
    v[6] = fmaxf(sqn + d1.z - 2.f * g1.z, 0.f);
    v[7] = fmaxf(sqn + d1.w - 2.f * g1.w, 0.f);

    unsigned lo = 0u, hi = 0x47800000u;   // 65536.0f >> max d2 (~9e3)
    while (lo < hi) {
        const unsigned mid = (lo + hi) >> 1;
        const float piv = __uint_as_float(mid);
        int c = 0;
#pragma unroll
        for (int i = 0; i < 8; ++i) c += (v[i] <= piv) ? 1 : 0;
#pragma unroll
        for (int off = 32; off > 0; off >>= 1) c += __shfl_xor(c, off);
        if (c >= KSEL_CNT) hi = mid; else lo = mid + 1;
    }
    if (lane == 0)
        kth[(size_t)p * C_DIM + row] = sqrtf(fmaxf(__uint_as_float(lo), 1e-12f));
}

// ---------------------------------------------------------------------------
// Kernel 3: per-layer fp64 fixed-order sum of 4096 kth-distances.
// ---------------------------------------------------------------------------
__global__ __launch_bounds__(256)
void reduce_kernel(const float* __restrict__ kth, double* __restrict__ hsum) {
    __shared__ double sd[256];
    const int l = blockIdx.x;
    const float* base = kth + (size_t)l * B_DIM * C_DIM;
    double acc = 0.0;
    for (int i = threadIdx.x; i < B_DIM * C_DIM; i += 256)
        acc += (double)base[i];
    sd[threadIdx.x] = acc;
    __syncthreads();
    for (int sstep = 128; sstep > 0; sstep >>= 1) {
        if (threadIdx.x < sstep) sd[threadIdx.x] += sd[threadIdx.x + sstep];
        __syncthreads();
    }
    if (threadIdx.x == 0) hsum[l] = sd[0];
}

// ---------------------------------------------------------------------------
// Kernel 4: ents = log(S+1); var(d1,ddof=1)+var(d2,ddof=1).
// ---------------------------------------------------------------------------
__global__ void final_kernel(const double* __restrict__ hsum, float* __restrict__ out) {
    double ents[L_DIM];
    for (int l = 0; l < L_DIM; ++l) ents[l] = log(hsum[l] + 1.0);
    const double d1[2] = { ents[2] - ents[1], ents[3] - ents[2] };
    const double d2[4] = { ents[4] - ents[3], ents[5] - ents[4],
                           ents[6] - ents[5], ents[7] - ents[6] };
    const double m1 = (d1[0] + d1[1]) * 0.5;
    const double v1 = (d1[0] - m1) * (d1[0] - m1) + (d1[1] - m1) * (d1[1] - m1);
    double m2 = 0.0;
    for (int i = 0; i < 4; ++i) m2 += d2[i];
    m2 *= 0.25;
    double v2 = 0.0;
    for (int i = 0; i < 4; ++i) v2 += (d2[i] - m2) * (d2[i] - m2);
    v2 /= 3.0;
    out[0] = (float)(v1 + v2);
}

// ---------------------------------------------------------------------------
extern "C" void kernel_launch(void* const* d_in, const int* in_sizes, int n_in,
                              void* d_out, int out_size, void* d_ws, size_t ws_size,
                              hipStream_t stream) {
    const float* net = (const float*)d_in[0];
    float* out = (float*)d_out;
    char* ws = (char*)d_ws;

    double* hsum = (double*)ws;
    float*  diag = (float*)(ws + 4096);
    float*  kth  = (float*)(ws + 4096 + 131072);
    const size_t gOff = 4096 + 2 * 131072;
    float*  G    = (float*)(ws + gOff);

    const size_t perPair = (size_t)C_DIM * C_DIM * sizeof(float);
    const size_t avail = ws_size > gOff ? ws_size - gOff : 0;
    int chunk = (int)(avail / perPair);
    if (chunk > NPAIR) chunk = NPAIR;
    if (chunk < 1) chunk = 1;

    for (int p0 = 0; p0 < NPAIR; p0 += chunk) {
        const int np = (NPAIR - p0) < chunk ? (NPAIR - p0) : chunk;
        gram_mfma<<<dim3(10 * np), dim3(256), 0, stream>>>(net, G, diag, p0, np);
        select_kernel<<<dim3(C_DIM / 4, np), dim3(256), 0, stream>>>(G, diag, kth, p0);
    }
    reduce_kernel<<<dim3(L_DIM), dim3(256), 0, stream>>>(kth, hsum);
    final_kernel<<<dim3(1), dim3(1), 0, stream>>>(hsum, out);
}